// Round 6
// baseline (279.228 us; speedup 1.0000x reference)
//
#include <hip/hip_runtime.h>
#include <hip/hip_bf16.h>

// GraphSAGE forward:
//   wconv -> [count(u8-packed atomics) || linear1 MFMA] (fat kernel) -> scans -> fill ->
//   3x [agg gather-mean bf16 + MFMA GEMM(norm,relu)] -> linear2
// h/agg stored bf16; GEMMs via mfma_f32_16x16x32_bf16 (f32 accumulate); no LDS in GEMM.

#define NT 256
#define EILP 8

typedef __attribute__((ext_vector_type(8))) short bf16x8;
typedef __attribute__((ext_vector_type(4))) float f32x4;

__device__ __forceinline__ float bfbits2f(unsigned short b) {
    return __uint_as_float(((unsigned)b) << 16);
}
__device__ __forceinline__ unsigned short f2bfbits(float v) {
    __hip_bfloat16 b = __float2bfloat16(v);
    return *reinterpret_cast<unsigned short*>(&b);
}

// ---------------- MFMA GEMM body (device fn so it can be fused) ----------------
// block = 4 waves, wave = 32 rows x 64 cols (2 row-tiles x 4 col-tiles of 16x16x32 mfma).
// C/D: col = lane&15, row = (lane>>4)*4 + reg.

template<int A1F32>
__device__ __forceinline__ void gemm_body(
    const float* __restrict__ A1f, const unsigned short* __restrict__ A1b,
    int ldA1, int K1, const unsigned short* __restrict__ W1t,
    const unsigned short* __restrict__ A2b, const unsigned short* __restrict__ W2t,
    const float* __restrict__ bias, float* __restrict__ outF,
    unsigned short* __restrict__ outB, int n, int do_norm, int bid) {
    const int t = threadIdx.x;
    const int lane = t & 63;
    const int w = t >> 6;
    const int r16 = lane & 15;
    const int g = lane >> 4;
    const int row0 = bid * 128 + w * 32;

    f32x4 acc[2][4];
    #pragma unroll
    for (int i = 0; i < 2; ++i)
        #pragma unroll
        for (int j = 0; j < 4; ++j) {
            acc[i][j][0] = 0.f; acc[i][j][1] = 0.f; acc[i][j][2] = 0.f; acc[i][j][3] = 0.f;
        }

    int ra[2];
    #pragma unroll
    for (int rt = 0; rt < 2; ++rt) {
        int r = row0 + rt * 16 + r16;
        ra[rt] = (r < n) ? r : (n - 1);
    }

    #pragma unroll 1
    for (int kc = 0; kc < K1; kc += 32) {
        bf16x8 af[2];
        #pragma unroll
        for (int rt = 0; rt < 2; ++rt) {
            if (A1F32) {
                const float* p = &A1f[(size_t)ra[rt] * ldA1 + kc + g * 8];
                const float4 f0 = *(const float4*)p;
                const float4 f1 = *(const float4*)(p + 4);
                bf16x8 a;
                a[0] = (short)f2bfbits(f0.x); a[1] = (short)f2bfbits(f0.y);
                a[2] = (short)f2bfbits(f0.z); a[3] = (short)f2bfbits(f0.w);
                a[4] = (short)f2bfbits(f1.x); a[5] = (short)f2bfbits(f1.y);
                a[6] = (short)f2bfbits(f1.z); a[7] = (short)f2bfbits(f1.w);
                af[rt] = a;
            } else {
                af[rt] = *(const bf16x8*)&A1b[(size_t)ra[rt] * ldA1 + kc + g * 8];
            }
        }
        #pragma unroll
        for (int ct = 0; ct < 4; ++ct) {
            const bf16x8 bw = *(const bf16x8*)&W1t[(size_t)(ct * 16 + r16) * K1 + kc + g * 8];
            acc[0][ct] = __builtin_amdgcn_mfma_f32_16x16x32_bf16(af[0], bw, acc[0][ct], 0, 0, 0);
            acc[1][ct] = __builtin_amdgcn_mfma_f32_16x16x32_bf16(af[1], bw, acc[1][ct], 0, 0, 0);
        }
    }
    if (A2b) {
        #pragma unroll 1
        for (int kc = 0; kc < 64; kc += 32) {
            bf16x8 af[2];
            #pragma unroll
            for (int rt = 0; rt < 2; ++rt)
                af[rt] = *(const bf16x8*)&A2b[(size_t)ra[rt] * 64 + kc + g * 8];
            #pragma unroll
            for (int ct = 0; ct < 4; ++ct) {
                const bf16x8 bw = *(const bf16x8*)&W2t[(size_t)(ct * 16 + r16) * 64 + kc + g * 8];
                acc[0][ct] = __builtin_amdgcn_mfma_f32_16x16x32_bf16(af[0], bw, acc[0][ct], 0, 0, 0);
                acc[1][ct] = __builtin_amdgcn_mfma_f32_16x16x32_bf16(af[1], bw, acc[1][ct], 0, 0, 0);
            }
        }
    }

    float bcol[4];
    #pragma unroll
    for (int ct = 0; ct < 4; ++ct) bcol[ct] = bias[ct * 16 + r16];

    #pragma unroll
    for (int rt = 0; rt < 2; ++rt) {
        #pragma unroll
        for (int ct = 0; ct < 4; ++ct)
            #pragma unroll
            for (int reg = 0; reg < 4; ++reg) acc[rt][ct][reg] += bcol[ct];

        if (do_norm) {
            #pragma unroll
            for (int reg = 0; reg < 4; ++reg) {
                float ss = 0.f;
                #pragma unroll
                for (int ct = 0; ct < 4; ++ct) ss += acc[rt][ct][reg] * acc[rt][ct][reg];
                ss += __shfl_xor(ss, 1, 64);
                ss += __shfl_xor(ss, 2, 64);
                ss += __shfl_xor(ss, 4, 64);
                ss += __shfl_xor(ss, 8, 64);
                const float inv = 1.0f / fmaxf(sqrtf(ss), 1e-12f);
                #pragma unroll
                for (int ct = 0; ct < 4; ++ct)
                    acc[rt][ct][reg] = fmaxf(acc[rt][ct][reg] * inv, 0.0f);
            }
        }

        const int rbase = row0 + rt * 16 + g * 4;
        #pragma unroll
        for (int reg = 0; reg < 4; ++reg) {
            const int rr = rbase + reg;
            if (rr < n) {
                if (outB) {
                    #pragma unroll
                    for (int ct = 0; ct < 4; ++ct)
                        outB[(size_t)rr * 64 + ct * 16 + r16] = f2bfbits(acc[rt][ct][reg]);
                } else {
                    #pragma unroll
                    for (int ct = 0; ct < 4; ++ct)
                        outF[(size_t)rr * 64 + ct * 16 + r16] = acc[rt][ct][reg];
                }
            }
        }
    }
}

template<int A1F32>
__global__ __launch_bounds__(NT) void gemm_mfma(
    const float* __restrict__ A1f, const unsigned short* __restrict__ A1b,
    int ldA1, int K1, const unsigned short* __restrict__ W1t,
    const unsigned short* __restrict__ A2b, const unsigned short* __restrict__ W2t,
    const float* __restrict__ bias, float* __restrict__ outF,
    unsigned short* __restrict__ outB, int n, int do_norm) {
    gemm_body<A1F32>(A1f, A1b, ldA1, K1, W1t, A2b, W2t, bias, outF, outB, n, do_norm, blockIdx.x);
}

// ---------------- fused: count (u8-packed atomics) || linear1 ----------------

__global__ __launch_bounds__(NT) void count_lin1_kernel(
    const int* __restrict__ dst, unsigned* __restrict__ cnt4,
    unsigned char* __restrict__ rank, int m, int nCB,
    const float* __restrict__ x, const unsigned short* __restrict__ W1t,
    const float* __restrict__ b1, unsigned short* __restrict__ hbf, int n) {
    if ((int)blockIdx.x < nCB) {
        const int base = blockIdx.x * (NT * EILP) + threadIdx.x;
        int d[EILP];
        unsigned ro[EILP];
        #pragma unroll
        for (int p = 0; p < EILP; ++p) {
            const int e = base + p * NT;
            d[p] = (e < m) ? dst[e] : -1;
        }
        #pragma unroll
        for (int p = 0; p < EILP; ++p)
            if (d[p] >= 0) ro[p] = atomicAdd(&cnt4[d[p] >> 2], 1u << (8 * (d[p] & 3)));
        #pragma unroll
        for (int p = 0; p < EILP; ++p) {
            const int e = base + p * NT;
            if (e < m) rank[e] = (unsigned char)((ro[p] >> (8 * (d[p] & 3))) & 255u);
        }
    } else {
        gemm_body<1>(x, nullptr, 128, 128, W1t, nullptr, nullptr, b1,
                     nullptr, hbf, n, 0, (int)blockIdx.x - nCB);
    }
}

// ---------------- scans over packed u8 counters ----------------
// chunk = 256 words = 1024 nodes per block.

__global__ void reduce_chunk_kernel(const unsigned* __restrict__ cnt4, int* __restrict__ bsum,
                                    int nwords) {
    __shared__ int ws[4];
    const int t = threadIdx.x, lane = t & 63, wid = t >> 6;
    const int w = blockIdx.x * 256 + t;
    const unsigned v = (w < nwords) ? cnt4[w] : 0u;
    int s = (int)((v & 255u) + ((v >> 8) & 255u) + ((v >> 16) & 255u) + (v >> 24));
    #pragma unroll
    for (int off = 32; off > 0; off >>= 1) s += __shfl_xor(s, off, 64);
    if (lane == 0) ws[wid] = s;
    __syncthreads();
    if (t == 0) bsum[blockIdx.x] = ws[0] + ws[1] + ws[2] + ws[3];
}

__global__ void scan_bsums_kernel(const int* __restrict__ bsum, int* __restrict__ bexcl,
                                  int* __restrict__ row_ptr, int n, int nb) {
    __shared__ int w0;
    const int t = threadIdx.x, lane = t & 63, wid = t >> 6;
    const int v = (t < nb) ? bsum[t] : 0;
    int x = v;
    #pragma unroll
    for (int off = 1; off < 64; off <<= 1) {
        const int tt = __shfl_up(x, off, 64);
        if (lane >= off) x += tt;
    }
    if (wid == 0 && lane == 63) w0 = x;
    __syncthreads();
    const int incl = x + (wid ? w0 : 0);
    if (t < nb) bexcl[t] = incl - v;
    if (t == nb - 1) row_ptr[n] = incl;
}

__global__ void scan_apply_kernel(const unsigned* __restrict__ cnt4, const int* __restrict__ bexcl,
                                  int* __restrict__ row_ptr, int n, int nwords) {
    __shared__ int wsum[4];
    const int t = threadIdx.x, lane = t & 63, wid = t >> 6;
    const int w = blockIdx.x * 256 + t;
    const unsigned v = (w < nwords) ? cnt4[w] : 0u;
    const int c0 = v & 255u, c1 = (v >> 8) & 255u, c2 = (v >> 16) & 255u, c3 = v >> 24;
    const int tsum = c0 + c1 + c2 + c3;
    int x = tsum;
    #pragma unroll
    for (int off = 1; off < 64; off <<= 1) {
        const int tt = __shfl_up(x, off, 64);
        if (lane >= off) x += tt;
    }
    if (lane == 63) wsum[wid] = x;
    __syncthreads();
    int woff = 0;
    for (int ww = 0; ww < wid; ++ww) woff += wsum[ww];
    const int e = bexcl[blockIdx.x] + woff + (x - tsum);
    int4 o;
    o.x = e; o.y = e + c0; o.z = o.y + c1; o.w = o.z + c2;
    const int node = w * 4;
    if (node + 3 < n) *(int4*)&row_ptr[node] = o;
    else {
        if (node < n)     row_ptr[node]     = o.x;
        if (node + 1 < n) row_ptr[node + 1] = o.y;
        if (node + 2 < n) row_ptr[node + 2] = o.z;
    }
}

// ---------------- fill: 8 edges/thread, rank from u8 ----------------

__global__ void fill_kernel(const int* __restrict__ src, const int* __restrict__ dst,
                            const int* __restrict__ row_ptr, const unsigned char* __restrict__ rank,
                            int* __restrict__ csr, int m) {
    const int base = blockIdx.x * (NT * EILP) + threadIdx.x;
    int d[EILP], s[EILP], rk[EILP], rp[EILP];
    #pragma unroll
    for (int p = 0; p < EILP; ++p) {
        const int e = base + p * NT;
        if (e < m) { d[p] = dst[e]; s[p] = src[e]; rk[p] = rank[e]; }
        else d[p] = -1;
    }
    #pragma unroll
    for (int p = 0; p < EILP; ++p)
        if (d[p] >= 0) rp[p] = row_ptr[d[p]];
    #pragma unroll
    for (int p = 0; p < EILP; ++p)
        if (d[p] >= 0) csr[rp[p] + rk[p]] = s[p];
}

// ---------------- weight convert+transpose: Wt[col][k] bf16 ----------------

__global__ void wconv_kernel(const float* __restrict__ W1, const float* __restrict__ Wl,
                             const float* __restrict__ Wr, const float* __restrict__ W2,
                             unsigned short* __restrict__ out) {
    int i = blockIdx.x * blockDim.x + threadIdx.x;
    if (i >= 36864) return;
    float v;
    if (i < 8192) {
        const int col = i >> 7, k = i & 127;
        v = W1[k * 64 + col];
    } else if (i < 32768) {
        const int j = i - 8192;
        const int mm = j >> 13, r = j & 8191;
        const int isR = (r >> 12) & 1, q = r & 4095;
        const int col = q >> 6, k = q & 63;
        v = (isR ? Wr : Wl)[mm * 4096 + k * 64 + col];
    } else {
        const int q = i - 32768;
        const int col = q >> 6, k = q & 63;
        v = W2[k * 64 + col];
    }
    out[i] = f2bfbits(v);
}

// ---------------- aggregation: aggB[node] = bf16(mean over in-edges of h[src]) ----------------
// lane split: g=lane>>4 (edge slot), c=lane&15 (4 cols each). 4 edges per wave-load.

__global__ __launch_bounds__(NT) void agg_kernel(const unsigned short* __restrict__ h,
    const int* __restrict__ row_ptr, const int* __restrict__ csr,
    unsigned short* __restrict__ aggB, int n) {
    const int t = threadIdx.x;
    const int lane = t & 63;
    const int g = lane >> 4;
    const int c = lane & 15;
    const int gw = (blockIdx.x * NT + t) >> 6;
    const int nw = (gridDim.x * NT) >> 6;
    for (int node = gw; node < n; node += nw) {
        const int rs = row_ptr[node];
        const int re = row_ptr[node + 1];
        float a0 = 0.f, a1 = 0.f, a2 = 0.f, a3 = 0.f;
        int e = rs;
        for (; e + 16 <= re; e += 16) {
            const int s0 = csr[e + g];
            const int s1 = csr[e + 4 + g];
            const int s2 = csr[e + 8 + g];
            const int s3 = csr[e + 12 + g];
            const ushort4 v0 = *(const ushort4*)&h[(size_t)s0 * 64 + c * 4];
            const ushort4 v1 = *(const ushort4*)&h[(size_t)s1 * 64 + c * 4];
            const ushort4 v2 = *(const ushort4*)&h[(size_t)s2 * 64 + c * 4];
            const ushort4 v3 = *(const ushort4*)&h[(size_t)s3 * 64 + c * 4];
            a0 += (bfbits2f(v0.x) + bfbits2f(v1.x)) + (bfbits2f(v2.x) + bfbits2f(v3.x));
            a1 += (bfbits2f(v0.y) + bfbits2f(v1.y)) + (bfbits2f(v2.y) + bfbits2f(v3.y));
            a2 += (bfbits2f(v0.z) + bfbits2f(v1.z)) + (bfbits2f(v2.z) + bfbits2f(v3.z));
            a3 += (bfbits2f(v0.w) + bfbits2f(v1.w)) + (bfbits2f(v2.w) + bfbits2f(v3.w));
        }
        for (; e + 8 <= re; e += 8) {
            const int s0 = csr[e + g];
            const int s1 = csr[e + 4 + g];
            const ushort4 v0 = *(const ushort4*)&h[(size_t)s0 * 64 + c * 4];
            const ushort4 v1 = *(const ushort4*)&h[(size_t)s1 * 64 + c * 4];
            a0 += bfbits2f(v0.x) + bfbits2f(v1.x);
            a1 += bfbits2f(v0.y) + bfbits2f(v1.y);
            a2 += bfbits2f(v0.z) + bfbits2f(v1.z);
            a3 += bfbits2f(v0.w) + bfbits2f(v1.w);
        }
        for (; e + 4 <= re; e += 4) {
            const int s0 = csr[e + g];
            const ushort4 v0 = *(const ushort4*)&h[(size_t)s0 * 64 + c * 4];
            a0 += bfbits2f(v0.x);
            a1 += bfbits2f(v0.y);
            a2 += bfbits2f(v0.z);
            a3 += bfbits2f(v0.w);
        }
        const int r = re - e;
        if (g < r) {
            const int s0 = csr[e + g];
            const ushort4 v0 = *(const ushort4*)&h[(size_t)s0 * 64 + c * 4];
            a0 += bfbits2f(v0.x);
            a1 += bfbits2f(v0.y);
            a2 += bfbits2f(v0.z);
            a3 += bfbits2f(v0.w);
        }
        a0 += __shfl_xor(a0, 16, 64); a0 += __shfl_xor(a0, 32, 64);
        a1 += __shfl_xor(a1, 16, 64); a1 += __shfl_xor(a1, 32, 64);
        a2 += __shfl_xor(a2, 16, 64); a2 += __shfl_xor(a2, 32, 64);
        a3 += __shfl_xor(a3, 16, 64); a3 += __shfl_xor(a3, 32, 64);
        if (g == 0) {
            const float inv = (re > rs) ? (1.0f / (float)(re - rs)) : 0.0f;
            ushort4 o;
            o.x = f2bfbits(a0 * inv);
            o.y = f2bfbits(a1 * inv);
            o.z = f2bfbits(a2 * inv);
            o.w = f2bfbits(a3 * inv);
            *(ushort4*)&aggB[(size_t)node * 64 + c * 4] = o;
        }
    }
}

// ---------------- launch ----------------

extern "C" void kernel_launch(void* const* d_in, const int* in_sizes, int n_in,
                              void* d_out, int out_size, void* d_ws, size_t ws_size,
                              hipStream_t stream) {
    const float* x  = (const float*)d_in[0];
    const int*   ei = (const int*)  d_in[1];
    const float* W1 = (const float*)d_in[2];
    const float* b1 = (const float*)d_in[3];
    const float* Wl = (const float*)d_in[4];
    const float* bl = (const float*)d_in[5];
    const float* Wr = (const float*)d_in[6];
    const float* W2 = (const float*)d_in[7];
    const float* b2 = (const float*)d_in[8];
    float* out = (float*)d_out;

    const int n = in_sizes[0] / 128;   // 100000
    const int m = in_sizes[1] / 2;     // 1250000
    const int* src = ei;
    const int* dst = ei + m;

    char* ws = (char*)d_ws;
    size_t off = 0;
    auto alloc = [&](size_t bytes) -> void* {
        void* p = ws + off;
        off = (off + bytes + 255) & ~(size_t)255;
        return p;
    };
    unsigned short* aggB    = (unsigned short*)alloc((size_t)n * 64 * 2);
    unsigned short* hbf     = (unsigned short*)alloc((size_t)n * 64 * 2);
    int*            row_ptr = (int*)alloc((size_t)(n + 1) * sizeof(int));
    const int nwords = (n + 3) / 4;
    unsigned*       cnt4    = (unsigned*)alloc((size_t)nwords * 4);
    int*            bsum    = (int*)alloc(512);
    int*            bexcl   = (int*)alloc(512);
    unsigned char*  rank    = (unsigned char*)alloc((size_t)m);
    int*            csr     = (int*)alloc((size_t)m * sizeof(int));
    unsigned short* wt      = (unsigned short*)alloc(36864 * 2);

    const unsigned short* W1t = wt;
    const unsigned short* W2t = wt + 32768;

    hipMemsetAsync(cnt4, 0, (size_t)nwords * 4, stream);
    wconv_kernel<<<144, NT, 0, stream>>>(W1, Wl, Wr, W2, wt);

    const int eb8 = (m + NT * EILP - 1) / (NT * EILP);   // 611
    const int NB = (nwords + 255) / 256;                  // 98 (<=128 for scan_bsums)
    const int gtiles = (n + 127) / 128;                   // 782

    // fused: count (blocks 0..eb8) || linear1 h0 = x@W1+b1 -> hbf (blocks eb8..eb8+gtiles)
    count_lin1_kernel<<<eb8 + gtiles, NT, 0, stream>>>(dst, cnt4, rank, m, eb8,
                                                       x, W1t, b1, hbf, n);

    reduce_chunk_kernel<<<NB, NT, 0, stream>>>(cnt4, bsum, nwords);
    scan_bsums_kernel<<<1, 128, 0, stream>>>(bsum, bexcl, row_ptr, n, NB);
    scan_apply_kernel<<<NB, NT, 0, stream>>>(cnt4, bexcl, row_ptr, n, nwords);
    fill_kernel<<<eb8, NT, 0, stream>>>(src, dst, row_ptr, rank, csr, m);

    for (int i = 0; i < 3; ++i) {
        agg_kernel<<<2048, NT, 0, stream>>>(hbf, row_ptr, csr, aggB, n);
        const unsigned short* Wlt = wt + 8192 + (size_t)i * 8192;
        const unsigned short* Wrt = Wlt + 4096;
        gemm_mfma<0><<<gtiles, NT, 0, stream>>>(nullptr, aggB, 64, 64, Wlt,
                                                hbf, Wrt, bl + (size_t)i * 64,
                                                nullptr, hbf, n, 1);
    }
    gemm_mfma<0><<<gtiles, NT, 0, stream>>>(nullptr, hbf, 64, 64, W2t,
                                            nullptr, nullptr, b2, out, nullptr, n, 0);
}

// Round 7
// 239.767 us; speedup vs baseline: 1.1646x; 1.1646x over previous
//
#include <hip/hip_runtime.h>
#include <hip/hip_bf16.h>

// GraphSAGE forward:
//   atomic-free CSR build (bin-histogram -> column scan -> base scan -> bin scatter -> per-bucket CSR)
//   -> wconv -> linear1 (MFMA) -> 3x [agg gather-mean bf16 + MFMA GEMM(norm,relu)] -> linear2
// h/agg stored bf16; GEMMs via mfma_f32_16x16x32_bf16 (f32 accumulate); no LDS in GEMM.

#define NT 256
#define NBLK 128          // binning blocks (phase 1 & 3 must use identical chunking)
#define BCAP 2048         // max buckets supported (nbuck = ceil(n/64) = 1563 for n=100000)

typedef __attribute__((ext_vector_type(8))) short bf16x8;
typedef __attribute__((ext_vector_type(4))) float f32x4;

__device__ __forceinline__ float bfbits2f(unsigned short b) {
    return __uint_as_float(((unsigned)b) << 16);
}
__device__ __forceinline__ unsigned short f2bfbits(float v) {
    __hip_bfloat16 b = __float2bfloat16(v);
    return *reinterpret_cast<unsigned short*>(&b);
}

// ---------------- CSR build, atomic-free (binning) ----------------

// Phase 1: per-block LDS histogram of dst>>6 -> hist[block][nbuck] (coalesced dump).
__global__ __launch_bounds__(NT) void bin_hist_kernel(const int* __restrict__ dst, int m, int chunk,
                                                      int nbuck, unsigned* __restrict__ hist) {
    __shared__ unsigned lh[BCAP];
    const int t = threadIdx.x;
    for (int i = t; i < nbuck; i += NT) lh[i] = 0;
    __syncthreads();
    const int s0 = blockIdx.x * chunk;
    const int s1 = min(m, s0 + chunk);
    int e = s0 + t;
    for (; e + 3 * NT < s1; e += 4 * NT) {
        const int d0 = dst[e], d1 = dst[e + NT], d2 = dst[e + 2 * NT], d3 = dst[e + 3 * NT];
        atomicAdd(&lh[d0 >> 6], 1u);
        atomicAdd(&lh[d1 >> 6], 1u);
        atomicAdd(&lh[d2 >> 6], 1u);
        atomicAdd(&lh[d3 >> 6], 1u);
    }
    for (; e < s1; e += NT) atomicAdd(&lh[dst[e] >> 6], 1u);
    __syncthreads();
    unsigned* hrow = hist + (size_t)blockIdx.x * nbuck;
    for (int i = t; i < nbuck; i += NT) hrow[i] = lh[i];
}

// Phase 2a: per-bucket column scan over NBLK blocks (one wave per bucket, NBLK/64 rounds).
__global__ __launch_bounds__(NT) void col_scan_kernel(unsigned* __restrict__ hist,
                                                      unsigned* __restrict__ btotal, int nbuck) {
    const int k = (blockIdx.x * NT + threadIdx.x) >> 6;
    const int lane = threadIdx.x & 63;
    if (k >= nbuck) return;
    unsigned carry = 0;
    #pragma unroll
    for (int r = 0; r < NBLK / 64; ++r) {
        const int b = r * 64 + lane;
        const unsigned v = hist[(size_t)b * nbuck + k];
        unsigned x = v;
        #pragma unroll
        for (int off = 1; off < 64; off <<= 1) {
            const unsigned tt = __shfl_up(x, off, 64);
            if (lane >= off) x += tt;
        }
        hist[(size_t)b * nbuck + k] = carry + x - v;   // exclusive offset for (block b, bucket k)
        carry += __shfl(x, 63, 64);
    }
    if (lane == 0) btotal[k] = carry;
}

// Phase 2b: single-block exclusive scan of bucket totals -> bbase[0..nbuck]; row_ptr[n] = m.
__global__ void base_scan_kernel(const unsigned* __restrict__ btotal, unsigned* __restrict__ bbase,
                                 int* __restrict__ row_ptr, int n, int nbuck) {
    __shared__ unsigned wsum[16];
    __shared__ unsigned s_total;
    __shared__ unsigned s_carry;
    const int tid = threadIdx.x;
    const int lane = tid & 63;
    const int wid = tid >> 6;
    if (tid == 0) s_carry = 0;
    __syncthreads();
    for (int base = 0; base < nbuck; base += 1024) {
        const int i = base + tid;
        const unsigned v = (i < nbuck) ? btotal[i] : 0;
        unsigned x = v;
        #pragma unroll
        for (int off = 1; off < 64; off <<= 1) {
            const unsigned t = __shfl_up(x, off, 64);
            if (lane >= off) x += t;
        }
        if (lane == 63) wsum[wid] = x;
        __syncthreads();
        if (wid == 0) {
            const unsigned wv = (lane < 16) ? wsum[lane] : 0;
            unsigned wx = wv;
            #pragma unroll
            for (int off = 1; off < 16; off <<= 1) {
                const unsigned t = __shfl_up(wx, off, 64);
                if (lane >= off) wx += t;
            }
            if (lane == 15) s_total = wx;
            if (lane < 16) wsum[lane] = wx - wv;
        }
        __syncthreads();
        const unsigned wave_excl = wsum[wid];
        const unsigned carry = s_carry;
        if (i < nbuck) bbase[i] = carry + wave_excl + (x - v);
        __syncthreads();
        if (tid == 0) s_carry = carry + s_total;
        __syncthreads();
    }
    if (tid == 0) {
        bbase[nbuck] = s_carry;
        row_ptr[n] = (int)s_carry;
    }
}

// Phase 3: scatter edges into bucket-contiguous bins (LDS cursors; same chunking as phase 1).
__global__ __launch_bounds__(NT) void bin_scatter_kernel(const int* __restrict__ src,
    const int* __restrict__ dst, int m, int chunk, int nbuck,
    const unsigned* __restrict__ hist, const unsigned* __restrict__ bbase,
    int* __restrict__ bsrc, unsigned char* __restrict__ bdl) {
    __shared__ unsigned baseL[BCAP];
    __shared__ unsigned cur[BCAP];
    const int t = threadIdx.x;
    const unsigned* hrow = hist + (size_t)blockIdx.x * nbuck;
    for (int i = t; i < nbuck; i += NT) {
        baseL[i] = bbase[i] + hrow[i];
        cur[i] = 0;
    }
    __syncthreads();
    const int s0 = blockIdx.x * chunk;
    const int s1 = min(m, s0 + chunk);
    int e = s0 + t;
    for (; e + 3 * NT < s1; e += 4 * NT) {
        const int d0 = dst[e], d1 = dst[e + NT], d2 = dst[e + 2 * NT], d3 = dst[e + 3 * NT];
        const int a0 = src[e], a1 = src[e + NT], a2 = src[e + 2 * NT], a3 = src[e + 3 * NT];
        const unsigned p0 = baseL[d0 >> 6] + atomicAdd(&cur[d0 >> 6], 1u);
        bsrc[p0] = a0; bdl[p0] = (unsigned char)(d0 & 63);
        const unsigned p1 = baseL[d1 >> 6] + atomicAdd(&cur[d1 >> 6], 1u);
        bsrc[p1] = a1; bdl[p1] = (unsigned char)(d1 & 63);
        const unsigned p2 = baseL[d2 >> 6] + atomicAdd(&cur[d2 >> 6], 1u);
        bsrc[p2] = a2; bdl[p2] = (unsigned char)(d2 & 63);
        const unsigned p3 = baseL[d3 >> 6] + atomicAdd(&cur[d3 >> 6], 1u);
        bsrc[p3] = a3; bdl[p3] = (unsigned char)(d3 & 63);
    }
    for (; e < s1; e += NT) {
        const int d = dst[e], a = src[e];
        const unsigned p = baseL[d >> 6] + atomicAdd(&cur[d >> 6], 1u);
        bsrc[p] = a; bdl[p] = (unsigned char)(d & 63);
    }
}

// Phase 4: one block per bucket (64 nodes): count per node, scan, write row_ptr + csr.
__global__ __launch_bounds__(NT) void bucket_csr_kernel(const int* __restrict__ bsrc,
    const unsigned char* __restrict__ bdl, const unsigned* __restrict__ bbase,
    int* __restrict__ row_ptr, int* __restrict__ csr, int n) {
    __shared__ unsigned ncnt[64];
    __shared__ unsigned noff[64];
    __shared__ unsigned cur2[64];
    const int k = blockIdx.x;
    const int t = threadIdx.x;
    const unsigned base = bbase[k];
    const int cnt = (int)(bbase[k + 1] - base);
    if (t < 64) { ncnt[t] = 0; cur2[t] = 0; }
    __syncthreads();
    for (int i = t; i < cnt; i += NT) atomicAdd(&ncnt[bdl[base + i]], 1u);
    __syncthreads();
    if (t < 64) {
        const unsigned v = ncnt[t];
        unsigned x = v;
        #pragma unroll
        for (int off = 1; off < 64; off <<= 1) {
            const unsigned tt = __shfl_up(x, off, 64);
            if (t >= off) x += tt;
        }
        noff[t] = x - v;
        const int node = k * 64 + t;
        if (node < n) row_ptr[node] = (int)(base + x - v);
    }
    __syncthreads();
    for (int i = t; i < cnt; i += NT) {
        const int dl = bdl[base + i];
        const unsigned r = atomicAdd(&cur2[dl], 1u);
        csr[base + noff[dl] + r] = bsrc[base + i];
    }
}

// ---------------- weight convert+transpose: Wt[col][k] bf16 ----------------

__global__ void wconv_kernel(const float* __restrict__ W1, const float* __restrict__ Wl,
                             const float* __restrict__ Wr, const float* __restrict__ W2,
                             unsigned short* __restrict__ out) {
    int i = blockIdx.x * blockDim.x + threadIdx.x;
    if (i >= 36864) return;
    float v;
    if (i < 8192) {
        const int col = i >> 7, k = i & 127;
        v = W1[k * 64 + col];
    } else if (i < 32768) {
        const int j = i - 8192;
        const int mm = j >> 13, r = j & 8191;
        const int isR = (r >> 12) & 1, q = r & 4095;
        const int col = q >> 6, k = q & 63;
        v = (isR ? Wr : Wl)[mm * 4096 + k * 64 + col];
    } else {
        const int q = i - 32768;
        const int col = q >> 6, k = q & 63;
        v = W2[k * 64 + col];
    }
    out[i] = f2bfbits(v);
}

// ---------------- aggregation: aggB[node] = bf16(mean over in-edges of h[src]) ----------------
// lane split: g=lane>>4 (edge slot), c=lane&15 (4 cols each). 4 edges per wave-load.

__global__ __launch_bounds__(NT) void agg_kernel(const unsigned short* __restrict__ h,
    const int* __restrict__ row_ptr, const int* __restrict__ csr,
    unsigned short* __restrict__ aggB, int n) {
    const int t = threadIdx.x;
    const int lane = t & 63;
    const int g = lane >> 4;
    const int c = lane & 15;
    const int gw = (blockIdx.x * NT + t) >> 6;
    const int nw = (gridDim.x * NT) >> 6;
    for (int node = gw; node < n; node += nw) {
        const int rs = row_ptr[node];
        const int re = row_ptr[node + 1];
        float a0 = 0.f, a1 = 0.f, a2 = 0.f, a3 = 0.f;
        int e = rs;
        for (; e + 16 <= re; e += 16) {
            const int s0 = csr[e + g];
            const int s1 = csr[e + 4 + g];
            const int s2 = csr[e + 8 + g];
            const int s3 = csr[e + 12 + g];
            const ushort4 v0 = *(const ushort4*)&h[(size_t)s0 * 64 + c * 4];
            const ushort4 v1 = *(const ushort4*)&h[(size_t)s1 * 64 + c * 4];
            const ushort4 v2 = *(const ushort4*)&h[(size_t)s2 * 64 + c * 4];
            const ushort4 v3 = *(const ushort4*)&h[(size_t)s3 * 64 + c * 4];
            a0 += (bfbits2f(v0.x) + bfbits2f(v1.x)) + (bfbits2f(v2.x) + bfbits2f(v3.x));
            a1 += (bfbits2f(v0.y) + bfbits2f(v1.y)) + (bfbits2f(v2.y) + bfbits2f(v3.y));
            a2 += (bfbits2f(v0.z) + bfbits2f(v1.z)) + (bfbits2f(v2.z) + bfbits2f(v3.z));
            a3 += (bfbits2f(v0.w) + bfbits2f(v1.w)) + (bfbits2f(v2.w) + bfbits2f(v3.w));
        }
        for (; e + 8 <= re; e += 8) {
            const int s0 = csr[e + g];
            const int s1 = csr[e + 4 + g];
            const ushort4 v0 = *(const ushort4*)&h[(size_t)s0 * 64 + c * 4];
            const ushort4 v1 = *(const ushort4*)&h[(size_t)s1 * 64 + c * 4];
            a0 += bfbits2f(v0.x) + bfbits2f(v1.x);
            a1 += bfbits2f(v0.y) + bfbits2f(v1.y);
            a2 += bfbits2f(v0.z) + bfbits2f(v1.z);
            a3 += bfbits2f(v0.w) + bfbits2f(v1.w);
        }
        for (; e + 4 <= re; e += 4) {
            const int s0 = csr[e + g];
            const ushort4 v0 = *(const ushort4*)&h[(size_t)s0 * 64 + c * 4];
            a0 += bfbits2f(v0.x);
            a1 += bfbits2f(v0.y);
            a2 += bfbits2f(v0.z);
            a3 += bfbits2f(v0.w);
        }
        const int r = re - e;
        if (g < r) {
            const int s0 = csr[e + g];
            const ushort4 v0 = *(const ushort4*)&h[(size_t)s0 * 64 + c * 4];
            a0 += bfbits2f(v0.x);
            a1 += bfbits2f(v0.y);
            a2 += bfbits2f(v0.z);
            a3 += bfbits2f(v0.w);
        }
        a0 += __shfl_xor(a0, 16, 64); a0 += __shfl_xor(a0, 32, 64);
        a1 += __shfl_xor(a1, 16, 64); a1 += __shfl_xor(a1, 32, 64);
        a2 += __shfl_xor(a2, 16, 64); a2 += __shfl_xor(a2, 32, 64);
        a3 += __shfl_xor(a3, 16, 64); a3 += __shfl_xor(a3, 32, 64);
        if (g == 0) {
            const float inv = (re > rs) ? (1.0f / (float)(re - rs)) : 0.0f;
            ushort4 o;
            o.x = f2bfbits(a0 * inv);
            o.y = f2bfbits(a1 * inv);
            o.z = f2bfbits(a2 * inv);
            o.w = f2bfbits(a3 * inv);
            *(ushort4*)&aggB[(size_t)node * 64 + c * 4] = o;
        }
    }
}

// ---------------- MFMA GEMM: C[n,64] = A1@W1 [+ A2@W2] + bias; optional L2norm+relu ----------------
// block = 4 waves, wave = 32 rows x 64 cols (2 row-tiles x 4 col-tiles of 16x16x32 mfma).
// C/D: col = lane&15, row = (lane>>4)*4 + reg.

template<int A1F32>
__global__ __launch_bounds__(NT) void gemm_mfma(
    const float* __restrict__ A1f, const unsigned short* __restrict__ A1b,
    int ldA1, int K1, const unsigned short* __restrict__ W1t,
    const unsigned short* __restrict__ A2b, const unsigned short* __restrict__ W2t,
    const float* __restrict__ bias, float* __restrict__ outF,
    unsigned short* __restrict__ outB, int n, int do_norm) {
    const int t = threadIdx.x;
    const int lane = t & 63;
    const int w = t >> 6;
    const int r16 = lane & 15;
    const int g = lane >> 4;
    const int row0 = blockIdx.x * 128 + w * 32;

    f32x4 acc[2][4];
    #pragma unroll
    for (int i = 0; i < 2; ++i)
        #pragma unroll
        for (int j = 0; j < 4; ++j) {
            acc[i][j][0] = 0.f; acc[i][j][1] = 0.f; acc[i][j][2] = 0.f; acc[i][j][3] = 0.f;
        }

    int ra[2];
    #pragma unroll
    for (int rt = 0; rt < 2; ++rt) {
        int r = row0 + rt * 16 + r16;
        ra[rt] = (r < n) ? r : (n - 1);
    }

    #pragma unroll 1
    for (int kc = 0; kc < K1; kc += 32) {
        bf16x8 af[2];
        #pragma unroll
        for (int rt = 0; rt < 2; ++rt) {
            if (A1F32) {
                const float* p = &A1f[(size_t)ra[rt] * ldA1 + kc + g * 8];
                const float4 f0 = *(const float4*)p;
                const float4 f1 = *(const float4*)(p + 4);
                bf16x8 a;
                a[0] = (short)f2bfbits(f0.x); a[1] = (short)f2bfbits(f0.y);
                a[2] = (short)f2bfbits(f0.z); a[3] = (short)f2bfbits(f0.w);
                a[4] = (short)f2bfbits(f1.x); a[5] = (short)f2bfbits(f1.y);
                a[6] = (short)f2bfbits(f1.z); a[7] = (short)f2bfbits(f1.w);
                af[rt] = a;
            } else {
                af[rt] = *(const bf16x8*)&A1b[(size_t)ra[rt] * ldA1 + kc + g * 8];
            }
        }
        #pragma unroll
        for (int ct = 0; ct < 4; ++ct) {
            const bf16x8 bw = *(const bf16x8*)&W1t[(size_t)(ct * 16 + r16) * K1 + kc + g * 8];
            acc[0][ct] = __builtin_amdgcn_mfma_f32_16x16x32_bf16(af[0], bw, acc[0][ct], 0, 0, 0);
            acc[1][ct] = __builtin_amdgcn_mfma_f32_16x16x32_bf16(af[1], bw, acc[1][ct], 0, 0, 0);
        }
    }
    if (A2b) {
        #pragma unroll 1
        for (int kc = 0; kc < 64; kc += 32) {
            bf16x8 af[2];
            #pragma unroll
            for (int rt = 0; rt < 2; ++rt)
                af[rt] = *(const bf16x8*)&A2b[(size_t)ra[rt] * 64 + kc + g * 8];
            #pragma unroll
            for (int ct = 0; ct < 4; ++ct) {
                const bf16x8 bw = *(const bf16x8*)&W2t[(size_t)(ct * 16 + r16) * 64 + kc + g * 8];
                acc[0][ct] = __builtin_amdgcn_mfma_f32_16x16x32_bf16(af[0], bw, acc[0][ct], 0, 0, 0);
                acc[1][ct] = __builtin_amdgcn_mfma_f32_16x16x32_bf16(af[1], bw, acc[1][ct], 0, 0, 0);
            }
        }
    }

    float bcol[4];
    #pragma unroll
    for (int ct = 0; ct < 4; ++ct) bcol[ct] = bias[ct * 16 + r16];

    #pragma unroll
    for (int rt = 0; rt < 2; ++rt) {
        #pragma unroll
        for (int ct = 0; ct < 4; ++ct)
            #pragma unroll
            for (int reg = 0; reg < 4; ++reg) acc[rt][ct][reg] += bcol[ct];

        if (do_norm) {
            #pragma unroll
            for (int reg = 0; reg < 4; ++reg) {
                float ss = 0.f;
                #pragma unroll
                for (int ct = 0; ct < 4; ++ct) ss += acc[rt][ct][reg] * acc[rt][ct][reg];
                ss += __shfl_xor(ss, 1, 64);
                ss += __shfl_xor(ss, 2, 64);
                ss += __shfl_xor(ss, 4, 64);
                ss += __shfl_xor(ss, 8, 64);
                const float inv = 1.0f / fmaxf(sqrtf(ss), 1e-12f);
                #pragma unroll
                for (int ct = 0; ct < 4; ++ct)
                    acc[rt][ct][reg] = fmaxf(acc[rt][ct][reg] * inv, 0.0f);
            }
        }

        const int rbase = row0 + rt * 16 + g * 4;
        #pragma unroll
        for (int reg = 0; reg < 4; ++reg) {
            const int rr = rbase + reg;
            if (rr < n) {
                if (outB) {
                    #pragma unroll
                    for (int ct = 0; ct < 4; ++ct)
                        outB[(size_t)rr * 64 + ct * 16 + r16] = f2bfbits(acc[rt][ct][reg]);
                } else {
                    #pragma unroll
                    for (int ct = 0; ct < 4; ++ct)
                        outF[(size_t)rr * 64 + ct * 16 + r16] = acc[rt][ct][reg];
                }
            }
        }
    }
}

// ---------------- launch ----------------

extern "C" void kernel_launch(void* const* d_in, const int* in_sizes, int n_in,
                              void* d_out, int out_size, void* d_ws, size_t ws_size,
                              hipStream_t stream) {
    const float* x  = (const float*)d_in[0];
    const int*   ei = (const int*)  d_in[1];
    const float* W1 = (const float*)d_in[2];
    const float* b1 = (const float*)d_in[3];
    const float* Wl = (const float*)d_in[4];
    const float* bl = (const float*)d_in[5];
    const float* Wr = (const float*)d_in[6];
    const float* W2 = (const float*)d_in[7];
    const float* b2 = (const float*)d_in[8];
    float* out = (float*)d_out;

    const int n = in_sizes[0] / 128;   // 100000
    const int m = in_sizes[1] / 2;     // 1250000
    const int* src = ei;
    const int* dst = ei + m;

    const int nbuck = (n + 63) >> 6;   // 1563 (must be <= BCAP)

    char* ws = (char*)d_ws;
    size_t off = 0;
    auto alloc = [&](size_t bytes) -> void* {
        void* p = ws + off;
        off = (off + bytes + 255) & ~(size_t)255;
        return p;
    };
    unsigned short* aggB    = (unsigned short*)alloc((size_t)n * 64 * 2);
    unsigned short* hbf     = (unsigned short*)alloc((size_t)n * 64 * 2);
    int*            row_ptr = (int*)alloc((size_t)(n + 1) * sizeof(int));
    unsigned*       hist    = (unsigned*)alloc((size_t)NBLK * nbuck * 4);
    unsigned*       btotal  = (unsigned*)alloc((size_t)nbuck * 4);
    unsigned*       bbase   = (unsigned*)alloc((size_t)(nbuck + 1) * 4);
    int*            bsrc    = (int*)alloc((size_t)m * 4);
    unsigned char*  bdl     = (unsigned char*)alloc((size_t)m);
    int*            csr     = (int*)alloc((size_t)m * 4);
    unsigned short* wt      = (unsigned short*)alloc(36864 * 2);

    const unsigned short* W1t = wt;
    const unsigned short* W2t = wt + 32768;

    const int chunk = (m + NBLK - 1) / NBLK;                 // 9766
    const int csblocks = (nbuck * 64 + NT - 1) / NT;         // 391
    const int gtiles = (n + 127) / 128;                      // 782

    wconv_kernel<<<144, NT, 0, stream>>>(W1, Wl, Wr, W2, wt);

    // h0 = x @ W1 + b1 -> hbf (bf16)
    gemm_mfma<1><<<gtiles, NT, 0, stream>>>(x, nullptr, 128, 128, W1t,
                                            nullptr, nullptr, b1, nullptr, hbf, n, 0);

    // atomic-free CSR build
    bin_hist_kernel<<<NBLK, NT, 0, stream>>>(dst, m, chunk, nbuck, hist);
    col_scan_kernel<<<csblocks, NT, 0, stream>>>(hist, btotal, nbuck);
    base_scan_kernel<<<1, 1024, 0, stream>>>(btotal, bbase, row_ptr, n, nbuck);
    bin_scatter_kernel<<<NBLK, NT, 0, stream>>>(src, dst, m, chunk, nbuck, hist, bbase, bsrc, bdl);
    bucket_csr_kernel<<<nbuck, NT, 0, stream>>>(bsrc, bdl, bbase, row_ptr, csr, n);

    for (int i = 0; i < 3; ++i) {
        agg_kernel<<<2048, NT, 0, stream>>>(hbf, row_ptr, csr, aggB, n);
        const unsigned short* Wlt = wt + 8192 + (size_t)i * 8192;
        const unsigned short* Wrt = Wlt + 4096;
        gemm_mfma<0><<<gtiles, NT, 0, stream>>>(nullptr, aggB, 64, 64, Wlt,
                                                hbf, Wrt, bl + (size_t)i * 64,
                                                nullptr, hbf, n, 1);
    }
    gemm_mfma<0><<<gtiles, NT, 0, stream>>>(nullptr, hbf, 64, 64, W2t,
                                            nullptr, nullptr, b2, out, nullptr, n, 0);
}

// Round 8
// 235.757 us; speedup vs baseline: 1.1844x; 1.0170x over previous
//
#include <hip/hip_runtime.h>
#include <hip/hip_bf16.h>

// GraphSAGE forward:
//   atomic-free CSR build (bin-histogram -> column scan -> base scan -> bin scatter -> per-bucket CSR)
//   -> wconv -> linear1 (MFMA) -> 3x [agg gather-mean bf16 + MFMA GEMM(norm,relu)] -> linear2
// h/agg stored bf16; GEMMs via mfma_f32_16x16x32_bf16 (f32 accumulate); no LDS in GEMM.

#define NT 256
#define NBLK 512          // binning blocks (phase 1 & 3 must use identical chunking)
#define BCAP 2048         // max buckets supported (nbuck = ceil(n/64) = 1563 for n=100000)

typedef __attribute__((ext_vector_type(8))) short bf16x8;
typedef __attribute__((ext_vector_type(4))) float f32x4;

__device__ __forceinline__ float bfbits2f(unsigned short b) {
    return __uint_as_float(((unsigned)b) << 16);
}
__device__ __forceinline__ unsigned short f2bfbits(float v) {
    __hip_bfloat16 b = __float2bfloat16(v);
    return *reinterpret_cast<unsigned short*>(&b);
}

// ---------------- CSR build, atomic-free (binning) ----------------

// Phase 1: per-block LDS histogram of dst>>6 -> hist[block][nbuck] (coalesced dump).
// chunk is a multiple of 4; per-thread contiguous int4 loads.
__global__ __launch_bounds__(NT) void bin_hist_kernel(const int* __restrict__ dst, int m, int chunk,
                                                      int nbuck, unsigned* __restrict__ hist) {
    __shared__ unsigned lh[BCAP];
    const int t = threadIdx.x;
    for (int i = t; i < nbuck; i += NT) lh[i] = 0;
    __syncthreads();
    const int s0 = blockIdx.x * chunk;
    const int s1 = min(m, s0 + chunk);
    for (int e = s0 + t * 4; e < s1; e += NT * 4) {
        if (e + 3 < s1) {
            const int4 d = *(const int4*)&dst[e];
            atomicAdd(&lh[d.x >> 6], 1u);
            atomicAdd(&lh[d.y >> 6], 1u);
            atomicAdd(&lh[d.z >> 6], 1u);
            atomicAdd(&lh[d.w >> 6], 1u);
        } else {
            for (int q = e; q < s1; ++q) atomicAdd(&lh[dst[q] >> 6], 1u);
        }
    }
    __syncthreads();
    unsigned* hrow = hist + (size_t)blockIdx.x * nbuck;
    for (int i = t; i < nbuck; i += NT) hrow[i] = lh[i];
}

// Phase 2a: per-bucket column scan over NBLK blocks (one wave per bucket, NBLK/64 rounds).
__global__ __launch_bounds__(NT) void col_scan_kernel(unsigned* __restrict__ hist,
                                                      unsigned* __restrict__ btotal, int nbuck) {
    const int k = (blockIdx.x * NT + threadIdx.x) >> 6;
    const int lane = threadIdx.x & 63;
    if (k >= nbuck) return;
    unsigned carry = 0;
    #pragma unroll
    for (int r = 0; r < NBLK / 64; ++r) {
        const int b = r * 64 + lane;
        const unsigned v = hist[(size_t)b * nbuck + k];
        unsigned x = v;
        #pragma unroll
        for (int off = 1; off < 64; off <<= 1) {
            const unsigned tt = __shfl_up(x, off, 64);
            if (lane >= off) x += tt;
        }
        hist[(size_t)b * nbuck + k] = carry + x - v;   // exclusive offset for (block b, bucket k)
        carry += __shfl(x, 63, 64);
    }
    if (lane == 0) btotal[k] = carry;
}

// Phase 2b: single-block exclusive scan of bucket totals -> bbase[0..nbuck]; row_ptr[n] = m.
__global__ void base_scan_kernel(const unsigned* __restrict__ btotal, unsigned* __restrict__ bbase,
                                 int* __restrict__ row_ptr, int n, int nbuck) {
    __shared__ unsigned wsum[16];
    __shared__ unsigned s_total;
    __shared__ unsigned s_carry;
    const int tid = threadIdx.x;
    const int lane = tid & 63;
    const int wid = tid >> 6;
    if (tid == 0) s_carry = 0;
    __syncthreads();
    for (int base = 0; base < nbuck; base += 1024) {
        const int i = base + tid;
        const unsigned v = (i < nbuck) ? btotal[i] : 0;
        unsigned x = v;
        #pragma unroll
        for (int off = 1; off < 64; off <<= 1) {
            const unsigned t = __shfl_up(x, off, 64);
            if (lane >= off) x += t;
        }
        if (lane == 63) wsum[wid] = x;
        __syncthreads();
        if (wid == 0) {
            const unsigned wv = (lane < 16) ? wsum[lane] : 0;
            unsigned wx = wv;
            #pragma unroll
            for (int off = 1; off < 16; off <<= 1) {
                const unsigned t = __shfl_up(wx, off, 64);
                if (lane >= off) wx += t;
            }
            if (lane == 15) s_total = wx;
            if (lane < 16) wsum[lane] = wx - wv;
        }
        __syncthreads();
        const unsigned wave_excl = wsum[wid];
        const unsigned carry = s_carry;
        if (i < nbuck) bbase[i] = carry + wave_excl + (x - v);
        __syncthreads();
        if (tid == 0) s_carry = carry + s_total;
        __syncthreads();
    }
    if (tid == 0) {
        bbase[nbuck] = s_carry;
        row_ptr[n] = (int)s_carry;
    }
}

// Phase 3: scatter edges into bucket-contiguous bins as packed (src, dst&63) int2.
__global__ __launch_bounds__(NT) void bin_scatter_kernel(const int* __restrict__ src,
    const int* __restrict__ dst, int m, int chunk, int nbuck,
    const unsigned* __restrict__ hist, const unsigned* __restrict__ bbase,
    int2* __restrict__ bpack) {
    __shared__ unsigned baseL[BCAP];
    __shared__ unsigned cur[BCAP];
    const int t = threadIdx.x;
    const unsigned* hrow = hist + (size_t)blockIdx.x * nbuck;
    for (int i = t; i < nbuck; i += NT) {
        baseL[i] = bbase[i] + hrow[i];
        cur[i] = 0;
    }
    __syncthreads();
    const int s0 = blockIdx.x * chunk;
    const int s1 = min(m, s0 + chunk);
    for (int e = s0 + t * 4; e < s1; e += NT * 4) {
        if (e + 3 < s1) {
            const int4 d = *(const int4*)&dst[e];
            const int4 a = *(const int4*)&src[e];
            const unsigned p0 = baseL[d.x >> 6] + atomicAdd(&cur[d.x >> 6], 1u);
            bpack[p0] = make_int2(a.x, d.x & 63);
            const unsigned p1 = baseL[d.y >> 6] + atomicAdd(&cur[d.y >> 6], 1u);
            bpack[p1] = make_int2(a.y, d.y & 63);
            const unsigned p2 = baseL[d.z >> 6] + atomicAdd(&cur[d.z >> 6], 1u);
            bpack[p2] = make_int2(a.z, d.z & 63);
            const unsigned p3 = baseL[d.w >> 6] + atomicAdd(&cur[d.w >> 6], 1u);
            bpack[p3] = make_int2(a.w, d.w & 63);
        } else {
            for (int q = e; q < s1; ++q) {
                const int d = dst[q];
                const unsigned p = baseL[d >> 6] + atomicAdd(&cur[d >> 6], 1u);
                bpack[p] = make_int2(src[q], d & 63);
            }
        }
    }
}

// Phase 4: one block per bucket (64 nodes): count per node, scan, write row_ptr + csr.
__global__ __launch_bounds__(NT) void bucket_csr_kernel(const int2* __restrict__ bpack,
    const unsigned* __restrict__ bbase, int* __restrict__ row_ptr, int* __restrict__ csr, int n) {
    __shared__ unsigned ncnt[64];
    __shared__ unsigned noff[64];
    __shared__ unsigned cur2[64];
    const int k = blockIdx.x;
    const int t = threadIdx.x;
    const unsigned base = bbase[k];
    const int cnt = (int)(bbase[k + 1] - base);
    if (t < 64) { ncnt[t] = 0; cur2[t] = 0; }
    __syncthreads();
    for (int i = t; i < cnt; i += NT) atomicAdd(&ncnt[bpack[base + i].y], 1u);
    __syncthreads();
    if (t < 64) {
        const unsigned v = ncnt[t];
        unsigned x = v;
        #pragma unroll
        for (int off = 1; off < 64; off <<= 1) {
            const unsigned tt = __shfl_up(x, off, 64);
            if (t >= off) x += tt;
        }
        noff[t] = x - v;
        const int node = k * 64 + t;
        if (node < n) row_ptr[node] = (int)(base + x - v);
    }
    __syncthreads();
    for (int i = t; i < cnt; i += NT) {
        const int2 pr = bpack[base + i];
        const unsigned r = atomicAdd(&cur2[pr.y], 1u);
        csr[base + noff[pr.y] + r] = pr.x;
    }
}

// ---------------- weight convert+transpose: Wt[col][k] bf16 ----------------

__global__ void wconv_kernel(const float* __restrict__ W1, const float* __restrict__ Wl,
                             const float* __restrict__ Wr, const float* __restrict__ W2,
                             unsigned short* __restrict__ out) {
    int i = blockIdx.x * blockDim.x + threadIdx.x;
    if (i >= 36864) return;
    float v;
    if (i < 8192) {
        const int col = i >> 7, k = i & 127;
        v = W1[k * 64 + col];
    } else if (i < 32768) {
        const int j = i - 8192;
        const int mm = j >> 13, r = j & 8191;
        const int isR = (r >> 12) & 1, q = r & 4095;
        const int col = q >> 6, k = q & 63;
        v = (isR ? Wr : Wl)[mm * 4096 + k * 64 + col];
    } else {
        const int q = i - 32768;
        const int col = q >> 6, k = q & 63;
        v = W2[k * 64 + col];
    }
    out[i] = f2bfbits(v);
}

// ---------------- aggregation: aggB[node] = bf16(mean over in-edges of h[src]) ----------------
// lane split: g=lane>>4 (edge slot), c=lane&15 (4 cols each). 4 edges per wave-load.

__global__ __launch_bounds__(NT) void agg_kernel(const unsigned short* __restrict__ h,
    const int* __restrict__ row_ptr, const int* __restrict__ csr,
    unsigned short* __restrict__ aggB, int n) {
    const int t = threadIdx.x;
    const int lane = t & 63;
    const int g = lane >> 4;
    const int c = lane & 15;
    const int gw = (blockIdx.x * NT + t) >> 6;
    const int nw = (gridDim.x * NT) >> 6;
    for (int node = gw; node < n; node += nw) {
        const int rs = row_ptr[node];
        const int re = row_ptr[node + 1];
        float a0 = 0.f, a1 = 0.f, a2 = 0.f, a3 = 0.f;
        int e = rs;
        for (; e + 16 <= re; e += 16) {
            const int s0 = csr[e + g];
            const int s1 = csr[e + 4 + g];
            const int s2 = csr[e + 8 + g];
            const int s3 = csr[e + 12 + g];
            const ushort4 v0 = *(const ushort4*)&h[(size_t)s0 * 64 + c * 4];
            const ushort4 v1 = *(const ushort4*)&h[(size_t)s1 * 64 + c * 4];
            const ushort4 v2 = *(const ushort4*)&h[(size_t)s2 * 64 + c * 4];
            const ushort4 v3 = *(const ushort4*)&h[(size_t)s3 * 64 + c * 4];
            a0 += (bfbits2f(v0.x) + bfbits2f(v1.x)) + (bfbits2f(v2.x) + bfbits2f(v3.x));
            a1 += (bfbits2f(v0.y) + bfbits2f(v1.y)) + (bfbits2f(v2.y) + bfbits2f(v3.y));
            a2 += (bfbits2f(v0.z) + bfbits2f(v1.z)) + (bfbits2f(v2.z) + bfbits2f(v3.z));
            a3 += (bfbits2f(v0.w) + bfbits2f(v1.w)) + (bfbits2f(v2.w) + bfbits2f(v3.w));
        }
        for (; e + 8 <= re; e += 8) {
            const int s0 = csr[e + g];
            const int s1 = csr[e + 4 + g];
            const ushort4 v0 = *(const ushort4*)&h[(size_t)s0 * 64 + c * 4];
            const ushort4 v1 = *(const ushort4*)&h[(size_t)s1 * 64 + c * 4];
            a0 += bfbits2f(v0.x) + bfbits2f(v1.x);
            a1 += bfbits2f(v0.y) + bfbits2f(v1.y);
            a2 += bfbits2f(v0.z) + bfbits2f(v1.z);
            a3 += bfbits2f(v0.w) + bfbits2f(v1.w);
        }
        for (; e + 4 <= re; e += 4) {
            const int s0 = csr[e + g];
            const ushort4 v0 = *(const ushort4*)&h[(size_t)s0 * 64 + c * 4];
            a0 += bfbits2f(v0.x);
            a1 += bfbits2f(v0.y);
            a2 += bfbits2f(v0.z);
            a3 += bfbits2f(v0.w);
        }
        const int r = re - e;
        if (g < r) {
            const int s0 = csr[e + g];
            const ushort4 v0 = *(const ushort4*)&h[(size_t)s0 * 64 + c * 4];
            a0 += bfbits2f(v0.x);
            a1 += bfbits2f(v0.y);
            a2 += bfbits2f(v0.z);
            a3 += bfbits2f(v0.w);
        }
        a0 += __shfl_xor(a0, 16, 64); a0 += __shfl_xor(a0, 32, 64);
        a1 += __shfl_xor(a1, 16, 64); a1 += __shfl_xor(a1, 32, 64);
        a2 += __shfl_xor(a2, 16, 64); a2 += __shfl_xor(a2, 32, 64);
        a3 += __shfl_xor(a3, 16, 64); a3 += __shfl_xor(a3, 32, 64);
        if (g == 0) {
            const float inv = (re > rs) ? (1.0f / (float)(re - rs)) : 0.0f;
            ushort4 o;
            o.x = f2bfbits(a0 * inv);
            o.y = f2bfbits(a1 * inv);
            o.z = f2bfbits(a2 * inv);
            o.w = f2bfbits(a3 * inv);
            *(ushort4*)&aggB[(size_t)node * 64 + c * 4] = o;
        }
    }
}

// ---------------- MFMA GEMM: C[n,64] = A1@W1 [+ A2@W2] + bias; optional L2norm+relu ----------------
// block = 4 waves, wave = 32 rows x 64 cols (2 row-tiles x 4 col-tiles of 16x16x32 mfma).
// C/D: col = lane&15, row = (lane>>4)*4 + reg.

template<int A1F32>
__global__ __launch_bounds__(NT) void gemm_mfma(
    const float* __restrict__ A1f, const unsigned short* __restrict__ A1b,
    int ldA1, int K1, const unsigned short* __restrict__ W1t,
    const unsigned short* __restrict__ A2b, const unsigned short* __restrict__ W2t,
    const float* __restrict__ bias, float* __restrict__ outF,
    unsigned short* __restrict__ outB, int n, int do_norm) {
    const int t = threadIdx.x;
    const int lane = t & 63;
    const int w = t >> 6;
    const int r16 = lane & 15;
    const int g = lane >> 4;
    const int row0 = blockIdx.x * 128 + w * 32;

    f32x4 acc[2][4];
    #pragma unroll
    for (int i = 0; i < 2; ++i)
        #pragma unroll
        for (int j = 0; j < 4; ++j) {
            acc[i][j][0] = 0.f; acc[i][j][1] = 0.f; acc[i][j][2] = 0.f; acc[i][j][3] = 0.f;
        }

    int ra[2];
    #pragma unroll
    for (int rt = 0; rt < 2; ++rt) {
        int r = row0 + rt * 16 + r16;
        ra[rt] = (r < n) ? r : (n - 1);
    }

    #pragma unroll 1
    for (int kc = 0; kc < K1; kc += 32) {
        bf16x8 af[2];
        #pragma unroll
        for (int rt = 0; rt < 2; ++rt) {
            if (A1F32) {
                const float* p = &A1f[(size_t)ra[rt] * ldA1 + kc + g * 8];
                const float4 f0 = *(const float4*)p;
                const float4 f1 = *(const float4*)(p + 4);
                bf16x8 a;
                a[0] = (short)f2bfbits(f0.x); a[1] = (short)f2bfbits(f0.y);
                a[2] = (short)f2bfbits(f0.z); a[3] = (short)f2bfbits(f0.w);
                a[4] = (short)f2bfbits(f1.x); a[5] = (short)f2bfbits(f1.y);
                a[6] = (short)f2bfbits(f1.z); a[7] = (short)f2bfbits(f1.w);
                af[rt] = a;
            } else {
                af[rt] = *(const bf16x8*)&A1b[(size_t)ra[rt] * ldA1 + kc + g * 8];
            }
        }
        #pragma unroll
        for (int ct = 0; ct < 4; ++ct) {
            const bf16x8 bw = *(const bf16x8*)&W1t[(size_t)(ct * 16 + r16) * K1 + kc + g * 8];
            acc[0][ct] = __builtin_amdgcn_mfma_f32_16x16x32_bf16(af[0], bw, acc[0][ct], 0, 0, 0);
            acc[1][ct] = __builtin_amdgcn_mfma_f32_16x16x32_bf16(af[1], bw, acc[1][ct], 0, 0, 0);
        }
    }
    if (A2b) {
        #pragma unroll 1
        for (int kc = 0; kc < 64; kc += 32) {
            bf16x8 af[2];
            #pragma unroll
            for (int rt = 0; rt < 2; ++rt)
                af[rt] = *(const bf16x8*)&A2b[(size_t)ra[rt] * 64 + kc + g * 8];
            #pragma unroll
            for (int ct = 0; ct < 4; ++ct) {
                const bf16x8 bw = *(const bf16x8*)&W2t[(size_t)(ct * 16 + r16) * 64 + kc + g * 8];
                acc[0][ct] = __builtin_amdgcn_mfma_f32_16x16x32_bf16(af[0], bw, acc[0][ct], 0, 0, 0);
                acc[1][ct] = __builtin_amdgcn_mfma_f32_16x16x32_bf16(af[1], bw, acc[1][ct], 0, 0, 0);
            }
        }
    }

    float bcol[4];
    #pragma unroll
    for (int ct = 0; ct < 4; ++ct) bcol[ct] = bias[ct * 16 + r16];

    #pragma unroll
    for (int rt = 0; rt < 2; ++rt) {
        #pragma unroll
        for (int ct = 0; ct < 4; ++ct)
            #pragma unroll
            for (int reg = 0; reg < 4; ++reg) acc[rt][ct][reg] += bcol[ct];

        if (do_norm) {
            #pragma unroll
            for (int reg = 0; reg < 4; ++reg) {
                float ss = 0.f;
                #pragma unroll
                for (int ct = 0; ct < 4; ++ct) ss += acc[rt][ct][reg] * acc[rt][ct][reg];
                ss += __shfl_xor(ss, 1, 64);
                ss += __shfl_xor(ss, 2, 64);
                ss += __shfl_xor(ss, 4, 64);
                ss += __shfl_xor(ss, 8, 64);
                const float inv = 1.0f / fmaxf(sqrtf(ss), 1e-12f);
                #pragma unroll
                for (int ct = 0; ct < 4; ++ct)
                    acc[rt][ct][reg] = fmaxf(acc[rt][ct][reg] * inv, 0.0f);
            }
        }

        const int rbase = row0 + rt * 16 + g * 4;
        #pragma unroll
        for (int reg = 0; reg < 4; ++reg) {
            const int rr = rbase + reg;
            if (rr < n) {
                if (outB) {
                    #pragma unroll
                    for (int ct = 0; ct < 4; ++ct)
                        outB[(size_t)rr * 64 + ct * 16 + r16] = f2bfbits(acc[rt][ct][reg]);
                } else {
                    #pragma unroll
                    for (int ct = 0; ct < 4; ++ct)
                        outF[(size_t)rr * 64 + ct * 16 + r16] = acc[rt][ct][reg];
                }
            }
        }
    }
}

// ---------------- launch ----------------

extern "C" void kernel_launch(void* const* d_in, const int* in_sizes, int n_in,
                              void* d_out, int out_size, void* d_ws, size_t ws_size,
                              hipStream_t stream) {
    const float* x  = (const float*)d_in[0];
    const int*   ei = (const int*)  d_in[1];
    const float* W1 = (const float*)d_in[2];
    const float* b1 = (const float*)d_in[3];
    const float* Wl = (const float*)d_in[4];
    const float* bl = (const float*)d_in[5];
    const float* Wr = (const float*)d_in[6];
    const float* W2 = (const float*)d_in[7];
    const float* b2 = (const float*)d_in[8];
    float* out = (float*)d_out;

    const int n = in_sizes[0] / 128;   // 100000
    const int m = in_sizes[1] / 2;     // 1250000
    const int* src = ei;
    const int* dst = ei + m;

    const int nbuck = (n + 63) >> 6;   // 1563 (must be <= BCAP)

    char* ws = (char*)d_ws;
    size_t off = 0;
    auto alloc = [&](size_t bytes) -> void* {
        void* p = ws + off;
        off = (off + bytes + 255) & ~(size_t)255;
        return p;
    };
    unsigned short* aggB    = (unsigned short*)alloc((size_t)n * 64 * 2);
    unsigned short* hbf     = (unsigned short*)alloc((size_t)n * 64 * 2);
    int*            row_ptr = (int*)alloc((size_t)(n + 1) * sizeof(int));
    unsigned*       hist    = (unsigned*)alloc((size_t)NBLK * nbuck * 4);
    unsigned*       btotal  = (unsigned*)alloc((size_t)nbuck * 4);
    unsigned*       bbase   = (unsigned*)alloc((size_t)(nbuck + 1) * 4);
    int2*           bpack   = (int2*)alloc((size_t)m * 8);
    int*            csr     = (int*)alloc((size_t)m * 4);
    unsigned short* wt      = (unsigned short*)alloc(36864 * 2);

    const unsigned short* W1t = wt;
    const unsigned short* W2t = wt + 32768;

    const int chunk = (((m + NBLK - 1) / NBLK) + 3) & ~3;    // multiple of 4 for int4 loads
    const int csblocks = (nbuck * 64 + NT - 1) / NT;         // 391
    const int gtiles = (n + 127) / 128;                      // 782

    wconv_kernel<<<144, NT, 0, stream>>>(W1, Wl, Wr, W2, wt);

    // h0 = x @ W1 + b1 -> hbf (bf16)
    gemm_mfma<1><<<gtiles, NT, 0, stream>>>(x, nullptr, 128, 128, W1t,
                                            nullptr, nullptr, b1, nullptr, hbf, n, 0);

    // atomic-free CSR build
    bin_hist_kernel<<<NBLK, NT, 0, stream>>>(dst, m, chunk, nbuck, hist);
    col_scan_kernel<<<csblocks, NT, 0, stream>>>(hist, btotal, nbuck);
    base_scan_kernel<<<1, 1024, 0, stream>>>(btotal, bbase, row_ptr, n, nbuck);
    bin_scatter_kernel<<<NBLK, NT, 0, stream>>>(src, dst, m, chunk, nbuck, hist, bbase, bpack);
    bucket_csr_kernel<<<nbuck, NT, 0, stream>>>(bpack, bbase, row_ptr, csr, n);

    for (int i = 0; i < 3; ++i) {
        agg_kernel<<<2048, NT, 0, stream>>>(hbf, row_ptr, csr, aggB, n);
        const unsigned short* Wlt = wt + 8192 + (size_t)i * 8192;
        const unsigned short* Wrt = Wlt + 4096;
        gemm_mfma<0><<<gtiles, NT, 0, stream>>>(nullptr, aggB, 64, 64, Wlt,
                                                hbf, Wrt, bl + (size_t)i * 64,
                                                nullptr, hbf, n, 1);
    }
    gemm_mfma<0><<<gtiles, NT, 0, stream>>>(nullptr, hbf, 64, 64, W2t,
                                            nullptr, nullptr, b2, out, nullptr, n, 0);
}

// Round 9
// 227.125 us; speedup vs baseline: 1.2294x; 1.0380x over previous
//
#include <hip/hip_runtime.h>
#include <hip/hip_bf16.h>

// GraphSAGE forward:
//   two-level binned CSR build (bin1: batch-hist + packed u32 scatter to super-bucket regions;
//   sbase scan; bin2: per-super-bucket hist/scan -> row_ptr + csr, all L2-window-local)
//   -> wconv -> linear1 (MFMA) -> 3x [agg gather-mean bf16 + MFMA GEMM(norm,relu)] -> linear2
// h/agg stored bf16; GEMMs via mfma_f32_16x16x32_bf16 (f32 accumulate); no LDS in GEMM.

#define NT 256
#define BATCH 4096        // edges per bin1 block (NT * 16)
#define SBCAP 8192        // slots per super-bucket region (mean 6378, std ~80 -> 22 sigma margin)

typedef __attribute__((ext_vector_type(8))) short bf16x8;
typedef __attribute__((ext_vector_type(4))) float f32x4;

__device__ __forceinline__ float bfbits2f(unsigned short b) {
    return __uint_as_float(((unsigned)b) << 16);
}
__device__ __forceinline__ unsigned short f2bfbits(float v) {
    __hip_bfloat16 b = __float2bfloat16(v);
    return *reinterpret_cast<unsigned short*>(&b);
}

// ---------------- CSR build: two-level binning ----------------
// super-bucket = node >> 9 (512 nodes each); pack = (src << 9) | (node & 511)  [src<2^17 -> fits u32]

// Pass 1: per-block batch of 4096 edges; LDS hist over 196 super-buckets; one global
// atomic per (batch,bucket) reserves region space; packed scatter into bucket regions.
__global__ __launch_bounds__(NT) void bin1_kernel(const int* __restrict__ src,
    const int* __restrict__ dst, int m, unsigned* __restrict__ gcur,
    unsigned* __restrict__ bins) {
    __shared__ unsigned hist[256];
    __shared__ unsigned gbase[256];
    const int t = threadIdx.x;
    const int base = blockIdx.x * BATCH;
    hist[t] = 0;
    __syncthreads();
    int d[16], s[16];
    const int e0 = base + t * 16;
    const bool full = (base + BATCH) <= m;
    if (full) {
        #pragma unroll
        for (int q = 0; q < 4; ++q) {
            const int4 dv = *(const int4*)&dst[e0 + q * 4];
            const int4 sv = *(const int4*)&src[e0 + q * 4];
            d[q*4+0]=dv.x; d[q*4+1]=dv.y; d[q*4+2]=dv.z; d[q*4+3]=dv.w;
            s[q*4+0]=sv.x; s[q*4+1]=sv.y; s[q*4+2]=sv.z; s[q*4+3]=sv.w;
        }
        #pragma unroll
        for (int q = 0; q < 16; ++q) atomicAdd(&hist[d[q] >> 9], 1u);
    } else {
        #pragma unroll
        for (int q = 0; q < 16; ++q) {
            const int e = e0 + q;
            if (e < m) { d[q] = dst[e]; s[q] = src[e]; atomicAdd(&hist[d[q] >> 9], 1u); }
            else d[q] = -1;
        }
    }
    __syncthreads();
    {
        const unsigned h = hist[t];
        gbase[t] = h ? atomicAdd(&gcur[t], h) : 0u;
        hist[t] = 0;                       // reuse as per-bucket cursor
    }
    __syncthreads();
    if (full) {
        #pragma unroll
        for (int q = 0; q < 16; ++q) {
            const int b = d[q] >> 9;
            const unsigned slot = gbase[b] + atomicAdd(&hist[b], 1u);
            bins[(size_t)b * SBCAP + slot] = ((unsigned)s[q] << 9) | (unsigned)(d[q] & 511);
        }
    } else {
        #pragma unroll
        for (int q = 0; q < 16; ++q) {
            if (d[q] >= 0) {
                const int b = d[q] >> 9;
                const unsigned slot = gbase[b] + atomicAdd(&hist[b], 1u);
                bins[(size_t)b * SBCAP + slot] = ((unsigned)s[q] << 9) | (unsigned)(d[q] & 511);
            }
        }
    }
}

// sbase: exclusive scan of 196 super-bucket counts (1 block, 256 threads); row_ptr[n] = m.
__global__ void sbase_kernel(const unsigned* __restrict__ gcur, unsigned* __restrict__ sbase,
                             int* __restrict__ row_ptr, int n, int nsb, int m) {
    __shared__ unsigned wsum[4];
    const int t = threadIdx.x, lane = t & 63, wid = t >> 6;
    const unsigned v = (t < nsb) ? gcur[t] : 0u;
    unsigned x = v;
    #pragma unroll
    for (int o = 1; o < 64; o <<= 1) {
        const unsigned tt = __shfl_up(x, o, 64);
        if (lane >= o) x += tt;
    }
    if (lane == 63) wsum[wid] = x;
    __syncthreads();
    unsigned woff = 0;
    for (int w = 0; w < wid; ++w) woff += wsum[w];
    if (t < nsb) sbase[t] = woff + x - v;
    if (t == 0) row_ptr[n] = m;
}

// Pass 2: one block per super-bucket (512 nodes, ~25KB edge window — L2-resident):
// LDS hist -> scan -> row_ptr; scatter packed srcs into final csr order.
__global__ __launch_bounds__(NT) void bin2_kernel(const unsigned* __restrict__ bins,
    const unsigned* __restrict__ gcur, const unsigned* __restrict__ sbase,
    int* __restrict__ row_ptr, int* __restrict__ csr, int n) {
    __shared__ unsigned hist[512];
    __shared__ unsigned off[512];
    __shared__ unsigned cur[512];
    __shared__ unsigned wsum[4];
    const int k = blockIdx.x;
    const int t = threadIdx.x;
    const int lane = t & 63, wid = t >> 6;
    const int cnt = (int)gcur[k];
    const unsigned sb = sbase[k];
    const unsigned* reg = bins + (size_t)k * SBCAP;
    hist[2*t] = 0; hist[2*t+1] = 0;
    __syncthreads();
    for (int i = t; i < cnt; i += NT) atomicAdd(&hist[reg[i] & 511u], 1u);
    __syncthreads();
    const unsigned v0 = hist[2*t], v1 = hist[2*t+1];
    const unsigned ps = v0 + v1;
    unsigned x = ps;
    #pragma unroll
    for (int o = 1; o < 64; o <<= 1) {
        const unsigned tt = __shfl_up(x, o, 64);
        if (lane >= o) x += tt;
    }
    if (lane == 63) wsum[wid] = x;
    __syncthreads();
    unsigned woff = 0;
    for (int w = 0; w < wid; ++w) woff += wsum[w];
    const unsigned excl = woff + x - ps;
    off[2*t] = excl; off[2*t+1] = excl + v0;
    cur[2*t] = 0; cur[2*t+1] = 0;
    const int node = k * 512 + 2 * t;
    if (node < n)     row_ptr[node]     = (int)(sb + excl);
    if (node + 1 < n) row_ptr[node + 1] = (int)(sb + excl + v0);
    __syncthreads();
    for (int i = t; i < cnt; i += NT) {
        const unsigned u = reg[i];
        const unsigned l = u & 511u;
        const unsigned r = atomicAdd(&cur[l], 1u);
        csr[sb + off[l] + r] = (int)(u >> 9);
    }
}

// ---------------- weight convert+transpose: Wt[col][k] bf16 ----------------

__global__ void wconv_kernel(const float* __restrict__ W1, const float* __restrict__ Wl,
                             const float* __restrict__ Wr, const float* __restrict__ W2,
                             unsigned short* __restrict__ out) {
    int i = blockIdx.x * blockDim.x + threadIdx.x;
    if (i >= 36864) return;
    float v;
    if (i < 8192) {
        const int col = i >> 7, k = i & 127;
        v = W1[k * 64 + col];
    } else if (i < 32768) {
        const int j = i - 8192;
        const int mm = j >> 13, r = j & 8191;
        const int isR = (r >> 12) & 1, q = r & 4095;
        const int col = q >> 6, k = q & 63;
        v = (isR ? Wr : Wl)[mm * 4096 + k * 64 + col];
    } else {
        const int q = i - 32768;
        const int col = q >> 6, k = q & 63;
        v = W2[k * 64 + col];
    }
    out[i] = f2bfbits(v);
}

// ---------------- aggregation: aggB[node] = bf16(mean over in-edges of h[src]) ----------------
// lane split: g=lane>>4 (edge slot), c=lane&15 (4 cols each). 4 edges per wave-load.

__global__ __launch_bounds__(NT) void agg_kernel(const unsigned short* __restrict__ h,
    const int* __restrict__ row_ptr, const int* __restrict__ csr,
    unsigned short* __restrict__ aggB, int n) {
    const int t = threadIdx.x;
    const int lane = t & 63;
    const int g = lane >> 4;
    const int c = lane & 15;
    const int gw = (blockIdx.x * NT + t) >> 6;
    const int nw = (gridDim.x * NT) >> 6;
    for (int node = gw; node < n; node += nw) {
        const int rs = row_ptr[node];
        const int re = row_ptr[node + 1];
        float a0 = 0.f, a1 = 0.f, a2 = 0.f, a3 = 0.f;
        int e = rs;
        for (; e + 16 <= re; e += 16) {
            const int s0 = csr[e + g];
            const int s1 = csr[e + 4 + g];
            const int s2 = csr[e + 8 + g];
            const int s3 = csr[e + 12 + g];
            const ushort4 v0 = *(const ushort4*)&h[(size_t)s0 * 64 + c * 4];
            const ushort4 v1 = *(const ushort4*)&h[(size_t)s1 * 64 + c * 4];
            const ushort4 v2 = *(const ushort4*)&h[(size_t)s2 * 64 + c * 4];
            const ushort4 v3 = *(const ushort4*)&h[(size_t)s3 * 64 + c * 4];
            a0 += (bfbits2f(v0.x) + bfbits2f(v1.x)) + (bfbits2f(v2.x) + bfbits2f(v3.x));
            a1 += (bfbits2f(v0.y) + bfbits2f(v1.y)) + (bfbits2f(v2.y) + bfbits2f(v3.y));
            a2 += (bfbits2f(v0.z) + bfbits2f(v1.z)) + (bfbits2f(v2.z) + bfbits2f(v3.z));
            a3 += (bfbits2f(v0.w) + bfbits2f(v1.w)) + (bfbits2f(v2.w) + bfbits2f(v3.w));
        }
        for (; e + 8 <= re; e += 8) {
            const int s0 = csr[e + g];
            const int s1 = csr[e + 4 + g];
            const ushort4 v0 = *(const ushort4*)&h[(size_t)s0 * 64 + c * 4];
            const ushort4 v1 = *(const ushort4*)&h[(size_t)s1 * 64 + c * 4];
            a0 += bfbits2f(v0.x) + bfbits2f(v1.x);
            a1 += bfbits2f(v0.y) + bfbits2f(v1.y);
            a2 += bfbits2f(v0.z) + bfbits2f(v1.z);
            a3 += bfbits2f(v0.w) + bfbits2f(v1.w);
        }
        for (; e + 4 <= re; e += 4) {
            const int s0 = csr[e + g];
            const ushort4 v0 = *(const ushort4*)&h[(size_t)s0 * 64 + c * 4];
            a0 += bfbits2f(v0.x);
            a1 += bfbits2f(v0.y);
            a2 += bfbits2f(v0.z);
            a3 += bfbits2f(v0.w);
        }
        const int r = re - e;
        if (g < r) {
            const int s0 = csr[e + g];
            const ushort4 v0 = *(const ushort4*)&h[(size_t)s0 * 64 + c * 4];
            a0 += bfbits2f(v0.x);
            a1 += bfbits2f(v0.y);
            a2 += bfbits2f(v0.z);
            a3 += bfbits2f(v0.w);
        }
        a0 += __shfl_xor(a0, 16, 64); a0 += __shfl_xor(a0, 32, 64);
        a1 += __shfl_xor(a1, 16, 64); a1 += __shfl_xor(a1, 32, 64);
        a2 += __shfl_xor(a2, 16, 64); a2 += __shfl_xor(a2, 32, 64);
        a3 += __shfl_xor(a3, 16, 64); a3 += __shfl_xor(a3, 32, 64);
        if (g == 0) {
            const float inv = (re > rs) ? (1.0f / (float)(re - rs)) : 0.0f;
            ushort4 o;
            o.x = f2bfbits(a0 * inv);
            o.y = f2bfbits(a1 * inv);
            o.z = f2bfbits(a2 * inv);
            o.w = f2bfbits(a3 * inv);
            *(ushort4*)&aggB[(size_t)node * 64 + c * 4] = o;
        }
    }
}

// ---------------- MFMA GEMM: C[n,64] = A1@W1 [+ A2@W2] + bias; optional L2norm+relu ----------------
// block = 4 waves, wave = 32 rows x 64 cols (2 row-tiles x 4 col-tiles of 16x16x32 mfma).
// C/D: col = lane&15, row = (lane>>4)*4 + reg.

template<int A1F32>
__global__ __launch_bounds__(NT) void gemm_mfma(
    const float* __restrict__ A1f, const unsigned short* __restrict__ A1b,
    int ldA1, int K1, const unsigned short* __restrict__ W1t,
    const unsigned short* __restrict__ A2b, const unsigned short* __restrict__ W2t,
    const float* __restrict__ bias, float* __restrict__ outF,
    unsigned short* __restrict__ outB, int n, int do_norm) {
    const int t = threadIdx.x;
    const int lane = t & 63;
    const int w = t >> 6;
    const int r16 = lane & 15;
    const int g = lane >> 4;
    const int row0 = blockIdx.x * 128 + w * 32;

    f32x4 acc[2][4];
    #pragma unroll
    for (int i = 0; i < 2; ++i)
        #pragma unroll
        for (int j = 0; j < 4; ++j) {
            acc[i][j][0] = 0.f; acc[i][j][1] = 0.f; acc[i][j][2] = 0.f; acc[i][j][3] = 0.f;
        }

    int ra[2];
    #pragma unroll
    for (int rt = 0; rt < 2; ++rt) {
        int r = row0 + rt * 16 + r16;
        ra[rt] = (r < n) ? r : (n - 1);
    }

    #pragma unroll 1
    for (int kc = 0; kc < K1; kc += 32) {
        bf16x8 af[2];
        #pragma unroll
        for (int rt = 0; rt < 2; ++rt) {
            if (A1F32) {
                const float* p = &A1f[(size_t)ra[rt] * ldA1 + kc + g * 8];
                const float4 f0 = *(const float4*)p;
                const float4 f1 = *(const float4*)(p + 4);
                bf16x8 a;
                a[0] = (short)f2bfbits(f0.x); a[1] = (short)f2bfbits(f0.y);
                a[2] = (short)f2bfbits(f0.z); a[3] = (short)f2bfbits(f0.w);
                a[4] = (short)f2bfbits(f1.x); a[5] = (short)f2bfbits(f1.y);
                a[6] = (short)f2bfbits(f1.z); a[7] = (short)f2bfbits(f1.w);
                af[rt] = a;
            } else {
                af[rt] = *(const bf16x8*)&A1b[(size_t)ra[rt] * ldA1 + kc + g * 8];
            }
        }
        #pragma unroll
        for (int ct = 0; ct < 4; ++ct) {
            const bf16x8 bw = *(const bf16x8*)&W1t[(size_t)(ct * 16 + r16) * K1 + kc + g * 8];
            acc[0][ct] = __builtin_amdgcn_mfma_f32_16x16x32_bf16(af[0], bw, acc[0][ct], 0, 0, 0);
            acc[1][ct] = __builtin_amdgcn_mfma_f32_16x16x32_bf16(af[1], bw, acc[1][ct], 0, 0, 0);
        }
    }
    if (A2b) {
        #pragma unroll 1
        for (int kc = 0; kc < 64; kc += 32) {
            bf16x8 af[2];
            #pragma unroll
            for (int rt = 0; rt < 2; ++rt)
                af[rt] = *(const bf16x8*)&A2b[(size_t)ra[rt] * 64 + kc + g * 8];
            #pragma unroll
            for (int ct = 0; ct < 4; ++ct) {
                const bf16x8 bw = *(const bf16x8*)&W2t[(size_t)(ct * 16 + r16) * 64 + kc + g * 8];
                acc[0][ct] = __builtin_amdgcn_mfma_f32_16x16x32_bf16(af[0], bw, acc[0][ct], 0, 0, 0);
                acc[1][ct] = __builtin_amdgcn_mfma_f32_16x16x32_bf16(af[1], bw, acc[1][ct], 0, 0, 0);
            }
        }
    }

    float bcol[4];
    #pragma unroll
    for (int ct = 0; ct < 4; ++ct) bcol[ct] = bias[ct * 16 + r16];

    #pragma unroll
    for (int rt = 0; rt < 2; ++rt) {
        #pragma unroll
        for (int ct = 0; ct < 4; ++ct)
            #pragma unroll
            for (int reg = 0; reg < 4; ++reg) acc[rt][ct][reg] += bcol[ct];

        if (do_norm) {
            #pragma unroll
            for (int reg = 0; reg < 4; ++reg) {
                float ss = 0.f;
                #pragma unroll
                for (int ct = 0; ct < 4; ++ct) ss += acc[rt][ct][reg] * acc[rt][ct][reg];
                ss += __shfl_xor(ss, 1, 64);
                ss += __shfl_xor(ss, 2, 64);
                ss += __shfl_xor(ss, 4, 64);
                ss += __shfl_xor(ss, 8, 64);
                const float inv = 1.0f / fmaxf(sqrtf(ss), 1e-12f);
                #pragma unroll
                for (int ct = 0; ct < 4; ++ct)
                    acc[rt][ct][reg] = fmaxf(acc[rt][ct][reg] * inv, 0.0f);
            }
        }

        const int rbase = row0 + rt * 16 + g * 4;
        #pragma unroll
        for (int reg = 0; reg < 4; ++reg) {
            const int rr = rbase + reg;
            if (rr < n) {
                if (outB) {
                    #pragma unroll
                    for (int ct = 0; ct < 4; ++ct)
                        outB[(size_t)rr * 64 + ct * 16 + r16] = f2bfbits(acc[rt][ct][reg]);
                } else {
                    #pragma unroll
                    for (int ct = 0; ct < 4; ++ct)
                        outF[(size_t)rr * 64 + ct * 16 + r16] = acc[rt][ct][reg];
                }
            }
        }
    }
}

// ---------------- launch ----------------

extern "C" void kernel_launch(void* const* d_in, const int* in_sizes, int n_in,
                              void* d_out, int out_size, void* d_ws, size_t ws_size,
                              hipStream_t stream) {
    const float* x  = (const float*)d_in[0];
    const int*   ei = (const int*)  d_in[1];
    const float* W1 = (const float*)d_in[2];
    const float* b1 = (const float*)d_in[3];
    const float* Wl = (const float*)d_in[4];
    const float* bl = (const float*)d_in[5];
    const float* Wr = (const float*)d_in[6];
    const float* W2 = (const float*)d_in[7];
    const float* b2 = (const float*)d_in[8];
    float* out = (float*)d_out;

    const int n = in_sizes[0] / 128;   // 100000
    const int m = in_sizes[1] / 2;     // 1250000
    const int* src = ei;
    const int* dst = ei + m;

    const int nsb = (n + 511) >> 9;    // 196 super-buckets (must be <= 256)

    char* ws = (char*)d_ws;
    size_t off = 0;
    auto alloc = [&](size_t bytes) -> void* {
        void* p = ws + off;
        off = (off + bytes + 255) & ~(size_t)255;
        return p;
    };
    unsigned short* aggB    = (unsigned short*)alloc((size_t)n * 64 * 2);
    unsigned short* hbf     = (unsigned short*)alloc((size_t)n * 64 * 2);
    int*            row_ptr = (int*)alloc((size_t)(n + 1) * sizeof(int));
    unsigned*       gcur    = (unsigned*)alloc((size_t)nsb * 4);
    unsigned*       sbase   = (unsigned*)alloc((size_t)(nsb + 1) * 4);
    unsigned*       bins    = (unsigned*)alloc((size_t)nsb * SBCAP * 4);
    int*            csr     = (int*)alloc((size_t)m * 4);
    unsigned short* wt      = (unsigned short*)alloc(36864 * 2);

    const unsigned short* W1t = wt;
    const unsigned short* W2t = wt + 32768;

    hipMemsetAsync(gcur, 0, (size_t)nsb * 4, stream);

    const int nb1 = (m + BATCH - 1) / BATCH;   // 306
    const int gtiles = (n + 127) / 128;        // 782

    wconv_kernel<<<144, NT, 0, stream>>>(W1, Wl, Wr, W2, wt);

    // h0 = x @ W1 + b1 -> hbf (bf16)
    gemm_mfma<1><<<gtiles, NT, 0, stream>>>(x, nullptr, 128, 128, W1t,
                                            nullptr, nullptr, b1, nullptr, hbf, n, 0);

    // two-level binned CSR build
    bin1_kernel<<<nb1, NT, 0, stream>>>(src, dst, m, gcur, bins);
    sbase_kernel<<<1, 256, 0, stream>>>(gcur, sbase, row_ptr, n, nsb, m);
    bin2_kernel<<<nsb, NT, 0, stream>>>(bins, gcur, sbase, row_ptr, csr, n);

    for (int i = 0; i < 3; ++i) {
        agg_kernel<<<2048, NT, 0, stream>>>(hbf, row_ptr, csr, aggB, n);
        const unsigned short* Wlt = wt + 8192 + (size_t)i * 8192;
        const unsigned short* Wrt = Wlt + 4096;
        gemm_mfma<0><<<gtiles, NT, 0, stream>>>(nullptr, aggB, 64, 64, Wlt,
                                                hbf, Wrt, bl + (size_t)i * 64,
                                                nullptr, hbf, n, 1);
    }
    gemm_mfma<0><<<gtiles, NT, 0, stream>>>(nullptr, hbf, 64, 64, W2t,
                                            nullptr, nullptr, b2, out, nullptr, n, 0);
}